// Round 1
// baseline (195.291 us; speedup 1.0000x reference)
//
#include <hip/hip_runtime.h>
#include <stdint.h>

// Router: logits = x @ wg^T + gr @ gm^T ; std-normalized softmax; top-2;
// zero expert 7; renormalize. Outputs flat: gates[T,2] | indices[T,2] (as
// float) | logits[T,8].  T=16384, D=2048, E=8.
//
// R8 = FUSED single kernel. Evidence from R7 rocprof: top-5 dispatches are
// all 512MiB ws-poison fills (~79us each); both our kernels run <78us, so
// dur_us=190 includes harness fill time. The controllable overhead is the
// split-K ws round trip (4MB write + 4MB read) + second dispatch. Fix:
// move split-K inside the block.
//   Block = 512 threads (8 waves) = 32 tokens. Wave w owns column group w
//   (256 cols) of those 32 tokens -- per-wave inner loop is byte-identical
//   to R7's proven kernel 1 (nt x-loads, 32-VGPR wg slice, ping-pong
//   prefetch, butterfly reduce-scatter). Per batch, each wave drops its 64
//   partials into LDS (8KB). One __syncthreads, then threads 0..255 run the
//   proven epilogue (one thread per (token, expert)).

#define DCONST 2048
#define TOK_PER_BATCH 8
#define BATCHES 4

typedef float f32x4 __attribute__((ext_vector_type(4)));

__device__ __forceinline__ unsigned long long shfl_xor_u64(unsigned long long v, int m) {
    int lo = __shfl_xor((int)(uint32_t)v, m, 64);
    int hi = __shfl_xor((int)(uint32_t)(v >> 32), m, 64);
    return ((unsigned long long)(uint32_t)hi << 32) | (unsigned long long)(uint32_t)lo;
}

__global__ __launch_bounds__(512, 2)
void router_fused(const float* __restrict__ x,   // [T,2048]
                  const float* __restrict__ wg,  // [8,2048]
                  const float* __restrict__ gm,  // [8,8]
                  const float* __restrict__ gr,  // [T,8]
                  float* __restrict__ out,       // 2T gates | 2T idx | 8T logits
                  int T)
{
    const int wave  = threadIdx.x >> 6;
    const int lane  = threadIdx.x & 63;
    const int g     = wave;                  // column group (256 cols)
    const int tbase = blockIdx.x * 32;       // first of 32 tokens

    __shared__ float red[8 * 256];           // [wave][batch][64] partials

    // wg slice for this lane's 4 columns, all 8 experts: 32 VGPRs, once.
    const float* wgp = wg + g * 256 + (lane << 2);
    f32x4 w8[8];
    #pragma unroll
    for (int e = 0; e < 8; ++e)
        w8[e] = *(const f32x4*)(wgp + (size_t)e * DCONST);

    const float* xp = x + (size_t)tbase * DCONST + g * 256 + (lane << 2);

    f32x4 xa[4], xb[4];

    #define LOADH(buf, trow)                                                  \
        { _Pragma("unroll")                                                   \
          for (int i = 0; i < 4; ++i)                                         \
              buf[i] = __builtin_nontemporal_load(                            \
                  (const f32x4*)(xp + (size_t)((trow) + i) * DCONST)); }

    #define FMAH(buf, tloc0)                                                  \
        { _Pragma("unroll")                                                   \
          for (int i = 0; i < 4; ++i) {                                       \
              _Pragma("unroll")                                               \
              for (int e = 0; e < 8; ++e) {                                   \
                  float a = acc[((tloc0) + i) * 8 + e];                       \
                  a += buf[i].x * w8[e].x;                                    \
                  a += buf[i].y * w8[e].y;                                    \
                  a += buf[i].z * w8[e].z;                                    \
                  a += buf[i].w * w8[e].w;                                    \
                  acc[((tloc0) + i) * 8 + e] = a;                             \
              }                                                               \
          } }

    LOADH(xa, 0);
    LOADH(xb, 4);

    #pragma unroll 1
    for (int b = 0; b < BATCHES; ++b) {
        float acc[64];
        #pragma unroll
        for (int v = 0; v < 64; ++v) acc[v] = 0.f;

        FMAH(xa, 0);                       // tokens b*8 + 0..3
        if (b < BATCHES - 1) LOADH(xa, (b + 1) * 8);
        FMAH(xb, 4);                       // tokens b*8 + 4..7
        if (b < BATCHES - 1) LOADH(xb, (b + 1) * 8 + 4);

        // butterfly reduce-scatter: lane l ends with value l = tloc*8+e
        #pragma unroll
        for (int m = 1; m < 64; m <<= 1) {
            const bool up = (lane & m) != 0;
            #pragma unroll
            for (int v = 0; v < 64; v += 2 * m) {
                const float keep = up ? acc[v + m] : acc[v];
                const float send = up ? acc[v] : acc[v + m];
                const float got  = __shfl_xor(send, m, 64);
                acc[v] = keep + got;
            }
        }

        red[wave * 256 + b * 64 + lane] = acc[0];
    }

    __syncthreads();

    // ---------------- epilogue: threads 0..255, one per (token, expert) ---
    const int tid = threadIdx.x;
    if (tid < 256) {
        const int f  = lane & 7;
        const int tt = lane >> 3;
        const int t  = tbase + wave * 8 + tt;

        // sum the 8 column-group partials; red[w*256 + tid] is exactly
        // (token = tid>>3, expert = tid&7) of column group w.
        float logit = 0.f;
        #pragma unroll
        for (int w = 0; w < 8; ++w)
            logit += red[w * 256 + tid];

        // residual: logit += sum_e gr[t][e] * gm[f][e]
        const float4 ga = *(const float4*)(gr + (size_t)t * 8);
        const float4 gb = *(const float4*)(gr + (size_t)t * 8 + 4);
        const float4 ma = *(const float4*)(gm + f * 8);
        const float4 mb = *(const float4*)(gm + f * 8 + 4);
        logit += ga.x * ma.x + ga.y * ma.y + ga.z * ma.z + ga.w * ma.w
               + gb.x * mb.x + gb.y * mb.y + gb.z * mb.z + gb.w * mb.w;

        // logits output (offset 4T): out[4T + t*8 + f] = base + tbase*8 + tid
        out[(size_t)4 * T + (size_t)tbase * 8 + tid] = logit;

        // stats over the 8-lane expert group
        float s = logit;
        s += __shfl_xor(s, 1, 64);
        s += __shfl_xor(s, 2, 64);
        s += __shfl_xor(s, 4, 64);
        const float mean = s * 0.125f;
        float d2 = (logit - mean) * (logit - mean);
        d2 += __shfl_xor(d2, 1, 64);
        d2 += __shfl_xor(d2, 2, 64);
        d2 += __shfl_xor(d2, 4, 64);
        const float stdv = sqrtf(d2 / 7.0f);    // ddof=1

        // top-2 via order-preserving 64-bit keys; ties -> smaller index
        uint32_t ob = __float_as_uint(logit);
        ob = (ob & 0x80000000u) ? ~ob : (ob | 0x80000000u);
        unsigned long long k1 = ((unsigned long long)ob << 8) | (unsigned long long)(7 - f);
        unsigned long long k2 = 0ull;
        #pragma unroll
        for (int m = 1; m <= 4; m <<= 1) {
            const unsigned long long o1 = shfl_xor_u64(k1, m);
            const unsigned long long o2 = shfl_xor_u64(k2, m);
            const unsigned long long hi = k1 > o1 ? k1 : o1;
            const unsigned long long lo = k1 > o1 ? o1 : k1;
            const unsigned long long so = k2 > o2 ? k2 : o2;
            k1 = hi;
            k2 = lo > so ? lo : so;
        }
        const int i1 = 7 - (int)(k1 & 0xFFull);
        const int i2 = 7 - (int)(k2 & 0xFFull);
        uint32_t b1 = (uint32_t)(k1 >> 8), b2 = (uint32_t)(k2 >> 8);
        b1 = (b1 & 0x80000000u) ? (b1 ^ 0x80000000u) : ~b1;
        b2 = (b2 & 0x80000000u) ? (b2 ^ 0x80000000u) : ~b2;
        const float l1 = __uint_as_float(b1);
        const float l2 = __uint_as_float(b2);

        // gates: softmax + zero-expert-7 + renorm collapses to a sigmoid
        float g0, g1;
        if (i1 == 7)      { g0 = 0.f; g1 = 1.f; }
        else if (i2 == 7) { g0 = 1.f; g1 = 0.f; }
        else {
            const float p = 1.0f / (1.0f + __expf(-(l1 - l2) / stdv));
            g0 = p; g1 = 1.0f - p;
        }

        if (f == 0) out[(size_t)2 * t]             = g0;
        if (f == 1) out[(size_t)2 * t + 1]         = g1;
        if (f == 2) out[(size_t)2 * T + 2 * t]     = (float)i1;
        if (f == 3) out[(size_t)2 * T + 2 * t + 1] = (float)i2;
    }
}

extern "C" void kernel_launch(void* const* d_in, const int* in_sizes, int n_in,
                              void* d_out, int out_size, void* d_ws, size_t ws_size,
                              hipStream_t stream) {
    const float* x  = (const float*)d_in[0];
    const float* wg = (const float*)d_in[1];
    const float* gm = (const float*)d_in[2];
    const float* gr = (const float*)d_in[3];
    const int T = in_sizes[0] / DCONST;        // 16384

    const int blocks = T / 32;                 // 512 blocks x 512 threads
    router_fused<<<blocks, 512, 0, stream>>>(x, wg, gm, gr, (float*)out_size ? (float*)d_out : (float*)d_out, T);
    (void)d_ws; (void)ws_size; (void)n_in;
}